// Round 14
// baseline (254.335 us; speedup 1.0000x reference)
//
#include <hip/hip_runtime.h>

constexpr int N_ROWS = 131072;
constexpr int DIM    = 512;
constexpr int KP     = 512;
constexpr int BM     = 64;        // rows per block (4 independent waves x 16)
constexpr int NCB    = KP / 16;   // 32 col-blocks of 16 cols

constexpr float PSCALE = 131072.0f;            // 2^17: P -> fp8 normal range
constexpr float DFACT  = 1.52587890625e-5f;    // 2 / 2^17

typedef float f32x4 __attribute__((ext_vector_type(4)));

__device__ inline unsigned cvtpk_fp8(float a, float b) {
    unsigned r = 0;   // "+v": high 16 bits preserved (= 0)
    asm volatile("v_cvt_pk_fp8_f32 %0, %1, %2" : "+v"(r) : "v"(a), "v"(b));
    return r;
}

// ---------------------------------------------------------------------------
// prep: pn[c] = ||P[c]||^2 (fp32, unscaled); Pq = fp8(P * 2^17) in B-FRAGMENT
// order: 8B unit for (col c, k-octet l) at
//   cb*8192 + kk*512 + g*128 + cl*8,  cb=c/16, cl=c%16, kk=l>>2, g=l&3.
// One wave's B-frag load for (cb, kk) is then 512 B fully contiguous.
// ---------------------------------------------------------------------------
__global__ void prep_kernel(const float* __restrict__ P, float* __restrict__ pn,
                            unsigned char* __restrict__ Pq) {
    const int c = blockIdx.x, l = threadIdx.x;   // l = k-octet 0..63
    const float* row = P + (size_t)c * DIM;
    float4 a = *reinterpret_cast<const float4*>(row + l * 8);
    float4 b = *reinterpret_cast<const float4*>(row + l * 8 + 4);
    float s = a.x*a.x + a.y*a.y + a.z*a.z + a.w*a.w
            + b.x*b.x + b.y*b.y + b.z*b.z + b.w*b.w;
    unsigned lo = cvtpk_fp8(a.x * PSCALE, a.y * PSCALE)
                | (cvtpk_fp8(a.z * PSCALE, a.w * PSCALE) << 16);
    unsigned hi = cvtpk_fp8(b.x * PSCALE, b.y * PSCALE)
                | (cvtpk_fp8(b.z * PSCALE, b.w * PSCALE) << 16);
    unsigned long long v = (unsigned long long)lo | ((unsigned long long)hi << 32);
    const int cb = c >> 4, cl = c & 15;
    const size_t off = (size_t)cb * 8192 + (l >> 2) * 512 + (l & 3) * 128 + cl * 8;
    *reinterpret_cast<unsigned long long*>(Pq + off) = v;
#pragma unroll
    for (int o = 32; o > 0; o >>= 1) s += __shfl_down(s, o);
    if (l == 0) pn[c] = s;
}

// ---------------------------------------------------------------------------
// vq: BARRIER-FREE main loop. Each wave owns 16 rows; A = fp8(X) full K=512
// in 16 named i64 regs; 32 col-blocks x {16 coalesced L2 B-loads + 16 MFMA
// + register fold}. No LDS staging, no inter-wave sync until the epilogue.
// Loss analytic: sum(best_dist) + sum(||x||^2).
// ---------------------------------------------------------------------------
__global__ __launch_bounds__(256, 2)
void vq_kernel(const float* __restrict__ X, const float* __restrict__ P,
               const unsigned char* __restrict__ Pq, const float* __restrict__ pn,
               float* __restrict__ out, double* __restrict__ lsum) {
    __shared__ int   idx_s[BM];
    __shared__ float wls[4];

    const int tid  = threadIdx.x;
    const int lane = tid & 63;
    const int wid  = tid >> 6;    // 0..3
    const int lr   = lane & 15;   // A row-in-wave / B col-in-block
    const int lg   = lane >> 4;   // k-octet subgroup
    const size_t row0 = (size_t)blockIdx.x * BM;

    // ---- A: X -> fp8 in 16 NAMED i64 regs + ||x||^2 (fp32) ----
    float xsq = 0.f;
    const float* xb = X + (row0 + wid * 16 + lr) * DIM + lg * 8;

#define ALOAD(KK, areg)                                                        \
    long long areg;                                                            \
    {                                                                          \
        float4 v0 = *reinterpret_cast<const float4*>(xb + (KK) * 32);          \
        float4 v1 = *reinterpret_cast<const float4*>(xb + (KK) * 32 + 4);      \
        xsq += v0.x*v0.x + v0.y*v0.y + v0.z*v0.z + v0.w*v0.w                   \
             + v1.x*v1.x + v1.y*v1.y + v1.z*v1.z + v1.w*v1.w;                  \
        unsigned lo = cvtpk_fp8(v0.x, v0.y) | (cvtpk_fp8(v0.z, v0.w) << 16);   \
        unsigned hi = cvtpk_fp8(v1.x, v1.y) | (cvtpk_fp8(v1.z, v1.w) << 16);   \
        areg = (long long)((unsigned long long)lo |                            \
                           ((unsigned long long)hi << 32));                    \
    }
    ALOAD(0,  a0)  ALOAD(1,  a1)  ALOAD(2,  a2)  ALOAD(3,  a3)
    ALOAD(4,  a4)  ALOAD(5,  a5)  ALOAD(6,  a6)  ALOAD(7,  a7)
    ALOAD(8,  a8)  ALOAD(9,  a9)  ALOAD(10, a10) ALOAD(11, a11)
    ALOAD(12, a12) ALOAD(13, a13) ALOAD(14, a14) ALOAD(15, a15)
#undef ALOAD

    float bv0 = 3.4e38f, bv1 = 3.4e38f, bv2 = 3.4e38f, bv3 = 3.4e38f;
    int   bi0 = 0, bi1 = 0, bi2 = 0, bi3 = 0;

    // per-lane B base: this lane's (k-octet g, col lr) slot within a fragment
    const unsigned char* bq = Pq + lg * 128 + lr * 8;

#define BL(P_, T_) (*reinterpret_cast<const long long*>((P_) + (T_) * 512))

#pragma unroll 2
    for (int cb = 0; cb < NCB; ++cb) {
        const unsigned char* p0 = bq + (size_t)cb * 8192;
        const unsigned char* p1 = p0 + 4096;
        f32x4 acc = {0.f, 0.f, 0.f, 0.f};
        acc = __builtin_amdgcn_mfma_f32_16x16x32_fp8_fp8(a0,  BL(p0, 0), acc, 0, 0, 0);
        acc = __builtin_amdgcn_mfma_f32_16x16x32_fp8_fp8(a1,  BL(p0, 1), acc, 0, 0, 0);
        acc = __builtin_amdgcn_mfma_f32_16x16x32_fp8_fp8(a2,  BL(p0, 2), acc, 0, 0, 0);
        acc = __builtin_amdgcn_mfma_f32_16x16x32_fp8_fp8(a3,  BL(p0, 3), acc, 0, 0, 0);
        acc = __builtin_amdgcn_mfma_f32_16x16x32_fp8_fp8(a4,  BL(p0, 4), acc, 0, 0, 0);
        acc = __builtin_amdgcn_mfma_f32_16x16x32_fp8_fp8(a5,  BL(p0, 5), acc, 0, 0, 0);
        acc = __builtin_amdgcn_mfma_f32_16x16x32_fp8_fp8(a6,  BL(p0, 6), acc, 0, 0, 0);
        acc = __builtin_amdgcn_mfma_f32_16x16x32_fp8_fp8(a7,  BL(p0, 7), acc, 0, 0, 0);
        acc = __builtin_amdgcn_mfma_f32_16x16x32_fp8_fp8(a8,  BL(p1, 0), acc, 0, 0, 0);
        acc = __builtin_amdgcn_mfma_f32_16x16x32_fp8_fp8(a9,  BL(p1, 1), acc, 0, 0, 0);
        acc = __builtin_amdgcn_mfma_f32_16x16x32_fp8_fp8(a10, BL(p1, 2), acc, 0, 0, 0);
        acc = __builtin_amdgcn_mfma_f32_16x16x32_fp8_fp8(a11, BL(p1, 3), acc, 0, 0, 0);
        acc = __builtin_amdgcn_mfma_f32_16x16x32_fp8_fp8(a12, BL(p1, 4), acc, 0, 0, 0);
        acc = __builtin_amdgcn_mfma_f32_16x16x32_fp8_fp8(a13, BL(p1, 5), acc, 0, 0, 0);
        acc = __builtin_amdgcn_mfma_f32_16x16x32_fp8_fp8(a14, BL(p1, 6), acc, 0, 0, 0);
        acc = __builtin_amdgcn_mfma_f32_16x16x32_fp8_fp8(a15, BL(p1, 7), acc, 0, 0, 0);

        const float pnv = pn[cb * 16 + lr];
        const int   ci  = cb * 16 + lr;
        float d;
        d = fmaf(-DFACT, acc[0], pnv);
        if (d < bv0) { bv0 = d; bi0 = ci; }
        d = fmaf(-DFACT, acc[1], pnv);
        if (d < bv1) { bv1 = d; bi1 = ci; }
        d = fmaf(-DFACT, acc[2], pnv);
        if (d < bv2) { bv2 = d; bi2 = ci; }
        d = fmaf(-DFACT, acc[3], pnv);
        if (d < bv3) { bv3 = d; bi3 = ci; }
    }
#undef BL

    // ---- wave-private argmin across the 16 col-holding lanes ----
#define MERGE(bv, bi, SLOT)                                                    \
    {                                                                          \
        _Pragma("unroll")                                                      \
        for (int m = 1; m < 16; m <<= 1) {                                     \
            float ov = __shfl_xor(bv, m);                                      \
            int   oi = __shfl_xor(bi, m);                                      \
            if (ov < bv || (ov == bv && oi < bi)) { bv = ov; bi = oi; }        \
        }                                                                      \
        if (lr == 0) idx_s[wid * 16 + lg * 4 + (SLOT)] = bi;                   \
    }
    MERGE(bv0, bi0, 0) MERGE(bv1, bi1, 1) MERGE(bv2, bi2, 2) MERGE(bv3, bi3, 3)
#undef MERGE

    // loss partial: best dists (lr==0 lanes) + ||x||^2 (all lanes)
    float lcl = xsq + (lr == 0 ? bv0 + bv1 + bv2 + bv3 : 0.f);
#pragma unroll
    for (int o = 32; o > 0; o >>= 1) lcl += __shfl_down(lcl, o);
    if (lane == 0) wls[wid] = lcl;
    __syncthreads();
    if (tid == 0)
        atomicAdd(lsum, (double)wls[0] + (double)wls[1]
                      + (double)wls[2] + (double)wls[3]);

    // ---- epilogue: out[r] = P[idx[r]] (P is L2-hot) ----
#pragma unroll 4
    for (int i = 0; i < 32; ++i) {
        int q = tid + i * 256;            // 64 rows x 128 float4
        int r = q >> 7, f4 = q & 127;
        float4 pv = *reinterpret_cast<const float4*>(
            P + (size_t)idx_s[r] * DIM + f4 * 4);
        *reinterpret_cast<float4*>(out + (row0 + r) * DIM + f4 * 4) = pv;
    }
}

__global__ void finalize_kernel(const double* __restrict__ lsum,
                                float* __restrict__ out_loss) {
    out_loss[0] = (float)(1.25 * lsum[0] / ((double)N_ROWS * (double)DIM));
}

extern "C" void kernel_launch(void* const* d_in, const int* in_sizes, int n_in,
                              void* d_out, int out_size, void* d_ws, size_t ws_size,
                              hipStream_t stream) {
    const float* X = (const float*)d_in[0];
    const float* P = (const float*)d_in[1];
    float* out = (float*)d_out;

    // ws: [0,8) lsum; [256,+2K) pn; [4096,+256K) Pq fp8 (fragment-ordered)
    double*        lsum = (double*)d_ws;
    float*         pn   = (float*)((char*)d_ws + 256);
    unsigned char* Pq   = (unsigned char*)d_ws + 4096;

    (void)hipMemsetAsync(d_ws, 0, 64, stream);
    prep_kernel<<<KP, 64, 0, stream>>>(P, pn, Pq);
    vq_kernel<<<N_ROWS / BM, 256, 0, stream>>>(X, P, Pq, pn, out, lsum);
    finalize_kernel<<<1, 1, 0, stream>>>(lsum, out + (size_t)N_ROWS * DIM);
    (void)hipMemcpyAsync(out + (size_t)N_ROWS * DIM + 1, P,
                         (size_t)KP * DIM * sizeof(float),
                         hipMemcpyDeviceToDevice, stream);
}

// Round 15
// 205.201 us; speedup vs baseline: 1.2394x; 1.2394x over previous
//
#include <hip/hip_runtime.h>

constexpr int N_ROWS = 131072;
constexpr int DIM    = 512;
constexpr int KP     = 512;
constexpr int BM     = 64;        // rows per block (4 waves x 16 rows)
constexpr int SC     = 32;        // cols per stage (full K=512 each)
constexpr int NS     = KP / SC;   // 16 stages
// stage = 32 cols x 512 K fp8 = 16 KB; double-buffered = 32 KB LDS -> 4 blk/CU

constexpr float PSCALE = 131072.0f;            // 2^17: P -> fp8 normal range
constexpr float DFACT  = 1.52587890625e-5f;    // 2 / 2^17

typedef float f32x4 __attribute__((ext_vector_type(4)));

__device__ inline unsigned cvtpk_fp8(float a, float b) {
    unsigned r = 0;   // "+v": high 16 bits preserved (= 0)
    asm volatile("v_cvt_pk_fp8_f32 %0, %1, %2" : "+v"(r) : "v"(a), "v"(b));
    return r;
}
__device__ inline void gload_lds16(const unsigned char* g, unsigned char* l) {
    // LDS dest must be WAVE-UNIFORM; HW adds lane*16.
    __builtin_amdgcn_global_load_lds(
        (const __attribute__((address_space(1))) unsigned*)g,
        (__attribute__((address_space(3))) unsigned*)l, 16, 0, 0);
}

// ---------------------------------------------------------------------------
// prep: pn[c] = ||P[c]||^2 (fp32, unscaled); Pq = fp8(P * 2^17) blocked by
// stage s=c/32 (32 cols x full K). 8B k-octet (c, l=k/8) -> byte
//   s*16384 + (l*32 + c%32)*8.   Exactly the linear order vq stages into LDS.
// ---------------------------------------------------------------------------
__global__ void prep_kernel(const float* __restrict__ P, float* __restrict__ pn,
                            unsigned char* __restrict__ Pq) {
    const int c = blockIdx.x, l = threadIdx.x;   // l = k-octet 0..63
    const float* row = P + (size_t)c * DIM;
    float4 a = *reinterpret_cast<const float4*>(row + l * 8);
    float4 b = *reinterpret_cast<const float4*>(row + l * 8 + 4);
    float s = a.x*a.x + a.y*a.y + a.z*a.z + a.w*a.w
            + b.x*b.x + b.y*b.y + b.z*b.z + b.w*b.w;
    unsigned lo = cvtpk_fp8(a.x * PSCALE, a.y * PSCALE)
                | (cvtpk_fp8(a.z * PSCALE, a.w * PSCALE) << 16);
    unsigned hi = cvtpk_fp8(b.x * PSCALE, b.y * PSCALE)
                | (cvtpk_fp8(b.z * PSCALE, b.w * PSCALE) << 16);
    unsigned long long v = (unsigned long long)lo | ((unsigned long long)hi << 32);
    const size_t off = (size_t)(c >> 5) * 16384 + ((size_t)l * 32 + (c & 31)) * 8;
    *reinterpret_cast<unsigned long long*>(Pq + off) = v;
#pragma unroll
    for (int o = 32; o > 0; o >>= 1) s += __shfl_down(s, o);
    if (l == 0) pn[c] = s;
}

// ---------------------------------------------------------------------------
// vq: 4 waves x 16 rows; A = fp8(X), full K=512, 16 named i64 regs (no spill
// under launch_bounds(256,2) -> 112 VGPR, r11/r13-proven). 16 stages of
// {32 cols x full K} (16 KB), double-buffered, counted vmcnt(4).
// 35 KB LDS -> 4 blocks/CU: independent block phases overlap on the CU.
// ---------------------------------------------------------------------------
__global__ __launch_bounds__(256, 2)
void vq_kernel(const float* __restrict__ X, const float* __restrict__ P,
               const unsigned char* __restrict__ Pq, const float* __restrict__ pn,
               float* __restrict__ out, double* __restrict__ lsum) {
    __shared__ __align__(16) unsigned char Bs[2][16384];  // 2 x 16 KB
    __shared__ float pn_s[KP];
    __shared__ int   idx_s[BM];
    __shared__ float wls[4];

    const int tid  = threadIdx.x;
    const int lane = tid & 63;
    const int wid  = tid >> 6;    // 0..3
    const int lr   = lane & 15;   // A row-in-wave / B col-in-tile
    const int lg   = lane >> 4;   // k-subgroup
    const size_t row0 = (size_t)blockIdx.x * BM;

    auto STAGE = [&](int s, int buf) {
        // 1024 x 16B units / 256 threads = 4 per thread; wave-uniform bases.
        const unsigned char* src = Pq + (size_t)s * 16384 + (wid * 64 + lane) * 16;
        unsigned char* dst = &Bs[buf][(wid * 64) * 16];   // wave-uniform base
#pragma unroll
        for (int i = 0; i < 4; ++i)
            gload_lds16(src + (size_t)i * 4096, dst + (size_t)i * 4096);
    };

    STAGE(0, 0);   // prefetch stage 0; latency hides under A-load

    if (tid < 256) { pn_s[tid] = pn[tid]; pn_s[tid + 256] = pn[tid + 256]; }

    // ---- A: X -> fp8 in 16 NAMED i64 regs + ||x||^2 (fp32) ----
    float xsq = 0.f;
    const float* xb = X + (row0 + wid * 16 + lr) * DIM + lg * 8;

#define ALOAD(KK, areg)                                                        \
    long long areg;                                                            \
    {                                                                          \
        float4 v0 = *reinterpret_cast<const float4*>(xb + (KK) * 32);          \
        float4 v1 = *reinterpret_cast<const float4*>(xb + (KK) * 32 + 4);      \
        xsq += v0.x*v0.x + v0.y*v0.y + v0.z*v0.z + v0.w*v0.w                   \
             + v1.x*v1.x + v1.y*v1.y + v1.z*v1.z + v1.w*v1.w;                  \
        unsigned lo = cvtpk_fp8(v0.x, v0.y) | (cvtpk_fp8(v0.z, v0.w) << 16);   \
        unsigned hi = cvtpk_fp8(v1.x, v1.y) | (cvtpk_fp8(v1.z, v1.w) << 16);   \
        areg = (long long)((unsigned long long)lo |                            \
                           ((unsigned long long)hi << 32));                    \
    }
    ALOAD(0,  a0)  ALOAD(1,  a1)  ALOAD(2,  a2)  ALOAD(3,  a3)
    ALOAD(4,  a4)  ALOAD(5,  a5)  ALOAD(6,  a6)  ALOAD(7,  a7)
    ALOAD(8,  a8)  ALOAD(9,  a9)  ALOAD(10, a10) ALOAD(11, a11)
    ALOAD(12, a12) ALOAD(13, a13) ALOAD(14, a14) ALOAD(15, a15)
#undef ALOAD

    float bv0 = 3.4e38f, bv1 = 3.4e38f, bv2 = 3.4e38f, bv3 = 3.4e38f;
    int   bi0 = 0, bi1 = 0, bi2 = 0, bi3 = 0;
    f32x4 acc0 = {0.f, 0.f, 0.f, 0.f}, acc1 = {0.f, 0.f, 0.f, 0.f};

#define MFMA_K(KK, areg)                                                       \
    {                                                                          \
        const unsigned char* bb = bsp + ((KK) * 4 + lg) * 256 + lr * 8;        \
        long long b0 = *reinterpret_cast<const long long*>(bb);                \
        long long b1 = *reinterpret_cast<const long long*>(bb + 128);          \
        acc0 = __builtin_amdgcn_mfma_f32_16x16x32_fp8_fp8(areg, b0, acc0, 0, 0, 0); \
        acc1 = __builtin_amdgcn_mfma_f32_16x16x32_fp8_fp8(areg, b1, acc1, 0, 0, 0); \
    }

#define FOLD_CT(accv, CT)                                                      \
    {                                                                          \
        const float pnv = pn_s[s * SC + (CT) * 16 + lr];                       \
        const int   ci  = s * SC + (CT) * 16 + lr;                             \
        float d;                                                               \
        d = fmaf(-DFACT, accv[0], pnv);                                        \
        if (d < bv0) { bv0 = d; bi0 = ci; }                                    \
        d = fmaf(-DFACT, accv[1], pnv);                                        \
        if (d < bv1) { bv1 = d; bi1 = ci; }                                    \
        d = fmaf(-DFACT, accv[2], pnv);                                        \
        if (d < bv2) { bv2 = d; bi2 = ci; }                                    \
        d = fmaf(-DFACT, accv[3], pnv);                                        \
        if (d < bv3) { bv3 = d; bi3 = ci; }                                    \
        accv = (f32x4){0.f, 0.f, 0.f, 0.f};                                    \
    }

    for (int s = 0; s < NS; ++s) {
        __builtin_amdgcn_s_barrier();            // all waves done with buf s&1
        if (s + 1 < NS) {
            STAGE(s + 1, (s + 1) & 1);           // issue next stage's 4 loads
            asm volatile("s_waitcnt vmcnt(4)" ::: "memory");  // stage s landed
        } else {
            asm volatile("s_waitcnt vmcnt(0)" ::: "memory");
        }
        __builtin_amdgcn_s_barrier();
        __builtin_amdgcn_sched_barrier(0);

        const unsigned char* bsp = Bs[s & 1];
        __builtin_amdgcn_s_setprio(1);
        MFMA_K(0,  a0)  MFMA_K(1,  a1)  MFMA_K(2,  a2)  MFMA_K(3,  a3)
        MFMA_K(4,  a4)  MFMA_K(5,  a5)  MFMA_K(6,  a6)  MFMA_K(7,  a7)
        MFMA_K(8,  a8)  MFMA_K(9,  a9)  MFMA_K(10, a10) MFMA_K(11, a11)
        MFMA_K(12, a12) MFMA_K(13, a13) MFMA_K(14, a14) MFMA_K(15, a15)
        __builtin_amdgcn_s_setprio(0);

        FOLD_CT(acc0, 0) FOLD_CT(acc1, 1)
    }
#undef MFMA_K
#undef FOLD_CT

    // ---- wave-private argmin across the 16 col-holding lanes ----
#define MERGE(bv, bi, SLOT)                                                    \
    {                                                                          \
        _Pragma("unroll")                                                      \
        for (int m = 1; m < 16; m <<= 1) {                                     \
            float ov = __shfl_xor(bv, m);                                      \
            int   oi = __shfl_xor(bi, m);                                      \
            if (ov < bv || (ov == bv && oi < bi)) { bv = ov; bi = oi; }        \
        }                                                                      \
        if (lr == 0) idx_s[wid * 16 + lg * 4 + (SLOT)] = bi;                   \
    }
    MERGE(bv0, bi0, 0) MERGE(bv1, bi1, 1) MERGE(bv2, bi2, 2) MERGE(bv3, bi3, 3)
#undef MERGE

    // loss partial: best dists (lr==0 lanes) + ||x||^2 (all lanes)
    float lcl = xsq + (lr == 0 ? bv0 + bv1 + bv2 + bv3 : 0.f);
#pragma unroll
    for (int o = 32; o > 0; o >>= 1) lcl += __shfl_down(lcl, o);
    if (lane == 0) wls[wid] = lcl;
    __syncthreads();
    if (tid == 0)
        atomicAdd(lsum, (double)wls[0] + (double)wls[1]
                      + (double)wls[2] + (double)wls[3]);

    // ---- epilogue: out[r] = P[idx[r]] (P is L2-hot) ----
#pragma unroll 4
    for (int i = 0; i < 32; ++i) {
        int q = tid + i * 256;            // 64 rows x 128 float4
        int r = q >> 7, f4 = q & 127;
        float4 pv = *reinterpret_cast<const float4*>(
            P + (size_t)idx_s[r] * DIM + f4 * 4);
        *reinterpret_cast<float4*>(out + (row0 + r) * DIM + f4 * 4) = pv;
    }
}

__global__ void finalize_kernel(const double* __restrict__ lsum,
                                float* __restrict__ out_loss) {
    out_loss[0] = (float)(1.25 * lsum[0] / ((double)N_ROWS * (double)DIM));
}

extern "C" void kernel_launch(void* const* d_in, const int* in_sizes, int n_in,
                              void* d_out, int out_size, void* d_ws, size_t ws_size,
                              hipStream_t stream) {
    const float* X = (const float*)d_in[0];
    const float* P = (const float*)d_in[1];
    float* out = (float*)d_out;

    // ws: [0,8) lsum; [256,+2K) pn; [4096,+256K) Pq fp8
    double*        lsum = (double*)d_ws;
    float*         pn   = (float*)((char*)d_ws + 256);
    unsigned char* Pq   = (unsigned char*)d_ws + 4096;

    (void)hipMemsetAsync(d_ws, 0, 64, stream);
    prep_kernel<<<KP, 64, 0, stream>>>(P, pn, Pq);
    vq_kernel<<<N_ROWS / BM, 256, 0, stream>>>(X, P, Pq, pn, out, lsum);
    finalize_kernel<<<1, 1, 0, stream>>>(lsum, out + (size_t)N_ROWS * DIM);
    (void)hipMemcpyAsync(out + (size_t)N_ROWS * DIM + 1, P,
                         (size_t)KP * DIM * sizeof(float),
                         hipMemcpyDeviceToDevice, stream);
}